// Round 15
// baseline (437.289 us; speedup 1.0000x reference)
//
#include <hip/hip_runtime.h>
#include <hip/hip_bf16.h>
#include <math.h>

// GPT decoder layer, MI355X/gfx950. bf16 MFMA GEMMs + fused flash attention.
// B=4 S=2048 D=1024 H=16 DH=64 F=4096.  Workspace layout (bytes):
//   [0,6M)      WqkvT  bf16 [3072][1024]   (pre-transposed, k-contiguous)
//   [6M,8M)     WoT    bf16 [1024][1024]
//   [8M,16M)    W1T    bf16 [4096][1024]
//   [16M,24M)   W2T    bf16 [1024][4096]
//   [24M,40M)   hbuf   bf16 [8192][1024]   (h -> attn_out -> h2, reused)
//   [40M,104M)  big    bf16                (QKV [8192][3072], later ff1 [8192][4096])

#define Bz 4
#define Sz 2048
#define Dz 1024
#define Hz 16
#define DHz 64
#define Fz 4096
#define Mz 8192

typedef float f32x4 __attribute__((ext_vector_type(4)));
typedef __bf16 bf16x8 __attribute__((ext_vector_type(8)));
typedef __bf16 bf16x4 __attribute__((ext_vector_type(4)));
typedef short s16x4 __attribute__((ext_vector_type(4)));

#define GLOAD_LDS16(g, l)                                                                   \
  __builtin_amdgcn_global_load_lds((const __attribute__((address_space(1))) unsigned int*)(g), \
                                   (__attribute__((address_space(3))) unsigned int*)(l), 16, 0, 0)

static __device__ __forceinline__ unsigned short f2bu(float f) {
  unsigned int u = __float_as_uint(f);
  u += 0x7fffu + ((u >> 16) & 1u);   // RNE to bf16
  return (unsigned short)(u >> 16);
}

static __device__ __forceinline__ f32x4 mfma32(bf16x8 a, bf16x8 b, f32x4 c) {
  return __builtin_amdgcn_mfma_f32_16x16x32_bf16(a, b, c, 0, 0, 0);
}
static __device__ __forceinline__ f32x4 mfma16(s16x4 a, s16x4 b, f32x4 c) {
#if __has_builtin(__builtin_amdgcn_mfma_f32_16x16x16bf16_1k)
  return __builtin_amdgcn_mfma_f32_16x16x16bf16_1k(a, b, c, 0, 0, 0);
#else
  asm("v_mfma_f32_16x16x16_bf16 %0, %1, %2, %0" : "+v"(c) : "v"(a), "v"(b));
  return c;
#endif
}

// hardware transpose read: lane l elem j <- lds[base + (l&15) + j*16 + (l>>4)*64] (bf16 elems)
template <int OFF>
static __device__ __forceinline__ s16x4 tr16(unsigned addr) {
  s16x4 r;
  asm volatile("ds_read_b64_tr_b16 %0, %1 offset:%2" : "=v"(r) : "v"(addr), "i"(OFF));
  return r;
}

// ---------------- weight packing ----------------

__global__ __launch_bounds__(256) void pack_qkv(
    const float* __restrict__ wq, const float* __restrict__ wk, const float* __restrict__ wv,
    unsigned short* __restrict__ outW)  // [3072][1024], row n = proj*1024 + h*64 + e, col = d
{
  __shared__ float tile[64][65];
  const int blk = blockIdx.x;       // 768 = 16 dchunk x 16 h x 3 proj
  const int dc = blk & 15;
  const int h  = (blk >> 4) & 15;
  const int p  = blk >> 8;
  const float* w = p == 0 ? wq : (p == 1 ? wk : wv);
  const int tid = threadIdx.x;
#pragma unroll
  for (int i = 0; i < 4; ++i) {
    int idx = i * 256 + tid;
    int dl = idx >> 4;
    int e0 = (idx & 15) * 4;
    const float4 v = *(const float4*)&w[(size_t)(h * 1024 + dc * 64 + dl) * 64 + e0];
    tile[dl][e0 + 0] = v.x; tile[dl][e0 + 1] = v.y;
    tile[dl][e0 + 2] = v.z; tile[dl][e0 + 3] = v.w;
  }
  __syncthreads();
#pragma unroll
  for (int i = 0; i < 4; ++i) {
    int idx = i * 256 + tid;
    int e = idx >> 4;
    int d0 = (idx & 15) * 4;
    ushort4 o;
    o.x = f2bu(tile[d0 + 0][e]); o.y = f2bu(tile[d0 + 1][e]);
    o.z = f2bu(tile[d0 + 2][e]); o.w = f2bu(tile[d0 + 3][e]);
    *(ushort4*)&outW[(size_t)(p * 1024 + h * 64 + e) * 1024 + dc * 64 + d0] = o;
  }
}

__global__ __launch_bounds__(256) void transpose_f32_to_bf16(
    const float* __restrict__ in, unsigned short* __restrict__ out, int R, int C)
{ // in [R][C] fp32 -> out [C][R] bf16
  __shared__ float tile[32][33];
  int c0 = blockIdx.x * 32, r0 = blockIdx.y * 32;
  int x = threadIdx.x, y = threadIdx.y;
#pragma unroll
  for (int i = 0; i < 32; i += 8)
    tile[y + i][x] = in[(size_t)(r0 + y + i) * C + c0 + x];
  __syncthreads();
#pragma unroll
  for (int i = 0; i < 32; i += 8)
    out[(size_t)(c0 + y + i) * R + r0 + x] = f2bu(tile[x][y + i]);
}

// ---------------- layernorm ----------------

__global__ __launch_bounds__(256) void ln_kernel(
    const float* __restrict__ x, const float* __restrict__ gamma, const float* __restrict__ beta,
    unsigned short* __restrict__ outH)
{
  const int row = blockIdx.x;
  const int tid = threadIdx.x;
  const float4 v = ((const float4*)(x + (size_t)row * Dz))[tid];
  float s = v.x + v.y + v.z + v.w;
  float s2 = v.x * v.x + v.y * v.y + v.z * v.z + v.w * v.w;
#pragma unroll
  for (int o = 32; o > 0; o >>= 1) {
    s += __shfl_xor(s, o);
    s2 += __shfl_xor(s2, o);
  }
  __shared__ float ss[4], ss2[4];
  if ((tid & 63) == 0) { ss[tid >> 6] = s; ss2[tid >> 6] = s2; }
  __syncthreads();
  s = ss[0] + ss[1] + ss[2] + ss[3];
  s2 = ss2[0] + ss2[1] + ss2[2] + ss2[3];
  const float mean = s * (1.0f / Dz);
  const float rstd = rsqrtf(s2 * (1.0f / Dz) - mean * mean + 1e-5f);
  const float4 g4 = ((const float4*)gamma)[tid];
  const float4 b4 = ((const float4*)beta)[tid];
  ushort4 o;
  o.x = f2bu((v.x - mean) * rstd * g4.x + b4.x);
  o.y = f2bu((v.y - mean) * rstd * g4.y + b4.y);
  o.z = f2bu((v.z - mean) * rstd * g4.z + b4.z);
  o.w = f2bu((v.w - mean) * rstd * g4.w + b4.w);
  ((ushort4*)(outH + (size_t)row * Dz))[tid] = o;
}

// ---------------- GEMM m97-structure: 128x128, BK=64, 256 thr / 4 waves, 4 blk/CU ----
// (R14-exact, best measured: total 421us, FFN1 < 104us.)
// Single-buffered, plain __syncthreads staging (m99/m100), unpinned compute
// (m141/R9), (row&7)/128B-span XOR swizzle (0 conflicts), bijective XCD swizzle.

enum { EPI_BF16 = 0, EPI_GELU_BF16 = 1, EPI_RES_F32 = 2, EPI_BIAS_RES_F32 = 3 };

template <int EPI>
__global__ __launch_bounds__(256, 4) void gemm128(
    const unsigned short* __restrict__ A,   // [M,K] bf16
    const unsigned short* __restrict__ BT,  // [N,K] bf16
    int M, int N, int K,
    const float* bias, const float* resid,  // resid/outf may alias: no __restrict__
    unsigned short* outb, float* outf)
{
  constexpr int BK = 64;
  __shared__ unsigned short As[128 * BK];  // [row][64k], 16B chunks, (row&7) XOR
  __shared__ unsigned short Bs[128 * BK];
  const int tid = threadIdx.x;
  const int lane = tid & 63;
  const int wid = tid >> 6;
  const int wm = (wid >> 1) * 64;
  const int wn = (wid & 1) * 64;
  const int rsel = lane & 15;
  const int kgrp = lane >> 4;

  // XCD-chunked bijective swizzle (nwg % 8 == 0 for all our grids)
  const int nwg = gridDim.x;
  const int bid = blockIdx.x;
  const int id2 = (bid & 7) * (nwg >> 3) + (bid >> 3);
  const int nbx = N / 128;
  const int n0 = (id2 % nbx) * 128;
  const int m0 = (id2 / nbx) * 128;

  f32x4 acc[4][4] = {};

  const int T = K >> 6;
  for (int t = 0; t < T; ++t) {
    if (t) __syncthreads();
    const int kOff = t * BK;
#pragma unroll
    for (int r = 0; r < 4; ++r) {          // 1024 chunks of 16B per matrix tile
      int gc = r * 256 + tid;
      int row = gc >> 3;
      int kcs = (gc & 7) ^ (row & 7);      // proven 128B-span swizzle (0 conflicts)
      GLOAD_LDS16(A + (size_t)(m0 + row) * K + kOff + kcs * 8, &As[gc * 8]);
      GLOAD_LDS16(BT + (size_t)(n0 + row) * K + kOff + kcs * 8, &Bs[gc * 8]);
    }
    __syncthreads();
#pragma unroll
    for (int kk = 0; kk < 2; ++kk) {
      bf16x8 af[4], bfr[4];
#pragma unroll
      for (int mf = 0; mf < 4; ++mf) {
        int ar = wm + mf * 16 + rsel;
        af[mf] = *(const bf16x8*)&As[ar * BK + (((kk * 4 + kgrp) ^ (ar & 7)) * 8)];
      }
#pragma unroll
      for (int nf = 0; nf < 4; ++nf) {
        int br = wn + nf * 16 + rsel;
        bfr[nf] = *(const bf16x8*)&Bs[br * BK + (((kk * 4 + kgrp) ^ (br & 7)) * 8)];
      }
      // unpinned: compiler emits fine-grained lgkmcnt and co-schedules with MFMA
#pragma unroll
      for (int mf = 0; mf < 4; ++mf)
#pragma unroll
        for (int nf = 0; nf < 4; ++nf)
          acc[mf][nf] = mfma32(af[mf], bfr[nf], acc[mf][nf]);
    }
  }

#pragma unroll
  for (int mf = 0; mf < 4; ++mf) {
#pragma unroll
    for (int nf = 0; nf < 4; ++nf) {
      const int n = n0 + wn + nf * 16 + rsel;
#pragma unroll
      for (int j = 0; j < 4; ++j) {
        const int m = m0 + wm + mf * 16 + kgrp * 4 + j;
        const size_t idx = (size_t)m * N + n;
        float v = acc[mf][nf][j];
        if constexpr (EPI == EPI_BF16) {
          outb[idx] = f2bu(v);
        } else if constexpr (EPI == EPI_GELU_BF16) {
          v += bias[n];
          v = 0.5f * v * (1.0f + erff(v * 0.70710678118654752f));
          outb[idx] = f2bu(v);
        } else if constexpr (EPI == EPI_RES_F32) {
          outf[idx] = v + resid[idx];
        } else {
          outf[idx] = v + bias[n] + resid[idx];
        }
      }
    }
  }
}

// ---------------- fused causal flash attention: VALU diet ----------------
// R14 base (104us, VALUBusy 65% + MfmaUtil 22% = issue-saturated). Two algebraic
// cuts, structure unchanged:
//  (1) FMA-fold: track running max over RAW scores (scale once after the 2-shuffle
//      reduce); p = exp2(fma(raw, SCL, -m)) merges the per-element xSCL and -m
//      into one v_fma (-16 VALU/proc). Mask sets raw=-inf -> exp2 -> 0, unchanged.
//  (2) l via MFMA ones-row: accL[s] += mfma16(ones, pb[kf]) (4 MFMA/set/tile on
//      the 22%-utilized MFMA pipe) replaces 16 psum adds + 2 serializing shuffles.
//      Deferred-rescale scales accL with accO (same semantics); final l=accL[0].
//      l now sums the bf16-rounded P — the same P PV uses (more self-consistent).

__global__ __launch_bounds__(256, 4) void attn_kernel(
    const unsigned short* __restrict__ QKV,  // [Mz][3072] bf16 (q|k|v, feature h*64+e)
    unsigned short* __restrict__ outA)       // [Mz][Dz]  bf16
{
  __shared__ unsigned short Kt[64 * 64];  // [key][d], 16B d-chunk XOR-swizzled by key&7
  __shared__ unsigned short Vs[64 * 64];  // subtiled for tr16 reads
  const int pi = blockIdx.x;  // 0..15
  const int hh = blockIdx.y;
  const int bb = blockIdx.z;
  const int tid = threadIdx.x;
  const int lane = tid & 63;
  const int w = tid >> 6;
  const int rsel = lane & 15;
  const int kgrp = lane >> 4;
  const int qt[2] = {pi, 31 - pi};

  bf16x8 qf0[2], qf1[2];
  int qg[2];
#pragma unroll
  for (int s = 0; s < 2; ++s) {
    qg[s] = qt[s] * 64 + w * 16 + rsel;
    const size_t rowQ = (size_t)(bb * Sz + qg[s]) * 3072 + hh * 64;
    qf0[s] = *(const bf16x8*)&QKV[rowQ + kgrp * 8];
    qf1[s] = *(const bf16x8*)&QKV[rowQ + 32 + kgrp * 8];
  }

  f32x4 accO[2][4] = {};  // [set][df]; O^T row=d=(df*16+kgrp*4+j), col=q=rsel
  f32x4 accL[2] = {};     // l accumulator via ones-row MFMA (all regs equal)
  float mr[2] = {-INFINITY, -INFINITY};

  const s16x4 ones = {(short)0x3F80, (short)0x3F80, (short)0x3F80, (short)0x3F80};

  auto vs3 = (__attribute__((address_space(3))) unsigned short*)Vs;
  const unsigned vbase = (unsigned)(uintptr_t)vs3 + (unsigned)lane * 8u;
  constexpr float SCL = 0.18033688011112042f;  // log2(e)/sqrt(64)

  // S^T + online softmax -> P^T bf16 B-frags. Raw-domain max; FMA-folded exp arg.
  auto proc = [&](const bf16x8& q0, const bf16x8& q1, float& mrun, f32x4* accS,
                  f32x4& accl, s16x4* pb, bool edge, int qgs, int kb) {
    f32x4 sc[4];
    __builtin_amdgcn_s_setprio(1);
#pragma unroll
    for (int kf = 0; kf < 4; ++kf) {
      int key = kf * 16 + rsel;
      bf16x8 k0 = *(const bf16x8*)&Kt[key * 64 + ((kgrp ^ (key & 7)) * 8)];
      bf16x8 k1 = *(const bf16x8*)&Kt[key * 64 + (((4 + kgrp) ^ (key & 7)) * 8)];
      f32x4 s = {};
      s = mfma32(k0, q0, s);
      s = mfma32(k1, q1, s);
      sc[kf] = s;
    }
    __builtin_amdgcn_s_setprio(0);
    float tmax = -INFINITY;
#pragma unroll
    for (int kf = 0; kf < 4; ++kf)
#pragma unroll
      for (int j = 0; j < 4; ++j) {
        if (edge) {
          int keyg = kb + kf * 16 + kgrp * 4 + j;
          if (keyg > qgs) sc[kf][j] = -INFINITY;
        }
        tmax = fmaxf(tmax, sc[kf][j]);
      }
    tmax = fmaxf(tmax, __shfl_xor(tmax, 16));
    tmax = fmaxf(tmax, __shfl_xor(tmax, 32));
    const float tmaxs = tmax * SCL;   // scale once, after the reduce
    // defer-rescale (T13): skip O/l rescale while max growth stays under 8 (log2 units)
    if (!__all(tmaxs <= mrun + 8.0f)) {
      const float mnew = fmaxf(mrun, tmaxs);
      const float corr = exp2f(mrun - mnew);
      accl *= corr;
#pragma unroll
      for (int df = 0; df < 4; ++df) accS[df] *= corr;
      mrun = mnew;
    }
#pragma unroll
    for (int kf = 0; kf < 4; ++kf) {
      bf16x4 pv;
#pragma unroll
      for (int j = 0; j < 4; ++j)
        pv[j] = (__bf16)exp2f(fmaf(sc[kf][j], SCL, -mrun));  // one v_fma + v_exp
      pb[kf] = __builtin_bit_cast(s16x4, pv);
    }
  };

  for (int kt = 0; kt <= qt[1]; ++kt) {
    const int kb = kt * 64;
    if (kt) __syncthreads();  // prev tile's LDS reads done before overwrite
    // stage K: LDS linear, global d-chunk XOR-swizzled by key&7
#pragma unroll
    for (int r = 0; r < 2; ++r) {
      int c = r * 256 + tid;
      int key = c >> 3;
      int dcs = (c & 7) ^ (key & 7);
      GLOAD_LDS16(QKV + (size_t)(bb * Sz + kb + key) * 3072 + 1024 + hh * 64 + dcs * 8,
                  &Kt[c * 8]);
    }
    // stage V: LDS linear; source permuted so LDS holds subtiled layout
#pragma unroll
    for (int r = 0; r < 2; ++r) {
      int c = r * 256 + tid;
      int key = ((c >> 3) & 15) * 4 + ((c >> 1) & 3);
      int d = (c >> 7) * 16 + (c & 1) * 8;
      GLOAD_LDS16(QKV + (size_t)(bb * Sz + kb + key) * 3072 + 2048 + hh * 64 + d,
                  &Vs[c * 8]);
    }
    __syncthreads();

    s16x4 pb[2][4];
#pragma unroll
    for (int s = 0; s < 2; ++s)
      if (kt <= qt[s])
        proc(qf0[s], qf1[s], mr[s], accO[s], accL[s], pb[s], kt == qt[s], qg[s], kb);

    // l += colsum(P) via ones-row MFMA (replaces psum VALU adds + shuffles)
    __builtin_amdgcn_s_setprio(1);
#pragma unroll
    for (int s = 0; s < 2; ++s)
      if (kt <= qt[s]) {
        accL[s] = mfma16(ones, pb[s][0], accL[s]);
        accL[s] = mfma16(ones, pb[s][1], accL[s]);
        accL[s] = mfma16(ones, pb[s][2], accL[s]);
        accL[s] = mfma16(ones, pb[s][3], accL[s]);
      }
    __builtin_amdgcn_s_setprio(0);

    // O^T += V^T @ P^T — V-frags shared by both q-sets
#pragma unroll
    for (int df = 0; df < 4; ++df) {
      unsigned a = vbase + df * 2048;
      s16x4 vf0 = tr16<0>(a);
      s16x4 vf1 = tr16<512>(a);
      s16x4 vf2 = tr16<1024>(a);
      s16x4 vf3 = tr16<1536>(a);
      asm volatile("s_waitcnt lgkmcnt(0)" ::: "memory");
      __builtin_amdgcn_sched_barrier(0);
      __builtin_amdgcn_s_setprio(1);
#pragma unroll
      for (int s = 0; s < 2; ++s) {
        if (kt <= qt[s]) {
          accO[s][df] = mfma16(vf0, pb[s][0], accO[s][df]);
          accO[s][df] = mfma16(vf1, pb[s][1], accO[s][df]);
          accO[s][df] = mfma16(vf2, pb[s][2], accO[s][df]);
          accO[s][df] = mfma16(vf3, pb[s][3], accO[s][df]);
        }
      }
      __builtin_amdgcn_s_setprio(0);
    }
  }

#pragma unroll
  for (int s = 0; s < 2; ++s) {
    const float rl = 1.0f / accL[s][0];
    const size_t orow = (size_t)(bb * Sz + qg[s]) * Dz + hh * 64;
#pragma unroll
    for (int df = 0; df < 4; ++df) {
      s16x4 o;
#pragma unroll
      for (int j = 0; j < 4; ++j) o[j] = (short)f2bu(accO[s][df][j] * rl);
      *(s16x4*)&outA[orow + df * 16 + kgrp * 4] = o;
    }
  }
}

// ---------------- launch ----------------

extern "C" void kernel_launch(void* const* d_in, const int* in_sizes, int n_in,
                              void* d_out, int out_size, void* d_ws, size_t ws_size,
                              hipStream_t stream) {
  const float* x   = (const float*)d_in[0];
  // d_in[1] = mask (causal, known) — unused
  const float* wq  = (const float*)d_in[2];
  const float* wk  = (const float*)d_in[3];
  const float* wv  = (const float*)d_in[4];
  const float* wo  = (const float*)d_in[5];
  const float* w1  = (const float*)d_in[6];
  const float* b1  = (const float*)d_in[7];
  const float* w2  = (const float*)d_in[8];
  const float* b2  = (const float*)d_in[9];
  const float* g1  = (const float*)d_in[10];
  const float* be1 = (const float*)d_in[11];
  const float* g2  = (const float*)d_in[12];
  const float* be2 = (const float*)d_in[13];
  float* out = (float*)d_out;

  char* ws = (char*)d_ws;
  unsigned short* WqkvT = (unsigned short*)(ws);
  unsigned short* WoT   = (unsigned short*)(ws + 6291456);
  unsigned short* W1T   = (unsigned short*)(ws + 8388608);
  unsigned short* W2T   = (unsigned short*)(ws + 16777216);
  unsigned short* hbuf  = (unsigned short*)(ws + 25165824);
  unsigned short* big   = (unsigned short*)(ws + 41943040);  // QKV, later ff1

  dim3 tb(32, 8);
  pack_qkv<<<768, 256, 0, stream>>>(wq, wk, wv, WqkvT);
  transpose_f32_to_bf16<<<dim3(32, 32), tb, 0, stream>>>(wo, WoT, 1024, 1024);
  transpose_f32_to_bf16<<<dim3(128, 32), tb, 0, stream>>>(w1, W1T, 1024, 4096);
  transpose_f32_to_bf16<<<dim3(32, 128), tb, 0, stream>>>(w2, W2T, 4096, 1024);

  ln_kernel<<<Mz, 256, 0, stream>>>(x, g1, be1, hbuf);
  gemm128<EPI_BF16><<<1536, 256, 0, stream>>>(
      hbuf, WqkvT, Mz, 3072, 1024, nullptr, nullptr, big, nullptr);
  attn_kernel<<<dim3(16, 16, 4), 256, 0, stream>>>(big, hbuf);
  gemm128<EPI_RES_F32><<<512, 256, 0, stream>>>(
      hbuf, WoT, Mz, 1024, 1024, nullptr, x, nullptr, out);
  ln_kernel<<<Mz, 256, 0, stream>>>(out, g2, be2, hbuf);
  gemm128<EPI_GELU_BF16><<<2048, 256, 0, stream>>>(
      hbuf, W1T, Mz, Fz, 1024, b1, nullptr, big, nullptr);
  gemm128<EPI_BIAS_RES_F32><<<512, 256, 0, stream>>>(
      big, W2T, Mz, 1024, Fz, b2, out, nullptr, out);
}

// Round 16
// 421.305 us; speedup vs baseline: 1.0379x; 1.0379x over previous
//
#include <hip/hip_runtime.h>
#include <hip/hip_bf16.h>
#include <math.h>

// GPT decoder layer, MI355X/gfx950. bf16 MFMA GEMMs + fused flash attention.
// B=4 S=2048 D=1024 H=16 DH=64 F=4096.  Workspace layout (bytes):
//   [0,6M)      WqkvT  bf16 [3072][1024]   (pre-transposed, k-contiguous)
//   [6M,8M)     WoT    bf16 [1024][1024]
//   [8M,16M)    W1T    bf16 [4096][1024]
//   [16M,24M)   W2T    bf16 [1024][4096]
//   [24M,40M)   hbuf   bf16 [8192][1024]   (h -> attn_out -> h2, reused)
//   [40M,104M)  big    bf16                (QKV [8192][3072], later ff1 [8192][4096])

#define Bz 4
#define Sz 2048
#define Dz 1024
#define Hz 16
#define DHz 64
#define Fz 4096
#define Mz 8192

typedef float f32x4 __attribute__((ext_vector_type(4)));
typedef __bf16 bf16x8 __attribute__((ext_vector_type(8)));
typedef __bf16 bf16x4 __attribute__((ext_vector_type(4)));
typedef short s16x4 __attribute__((ext_vector_type(4)));

#define GLOAD_LDS16(g, l)                                                                   \
  __builtin_amdgcn_global_load_lds((const __attribute__((address_space(1))) unsigned int*)(g), \
                                   (__attribute__((address_space(3))) unsigned int*)(l), 16, 0, 0)

static __device__ __forceinline__ unsigned short f2bu(float f) {
  unsigned int u = __float_as_uint(f);
  u += 0x7fffu + ((u >> 16) & 1u);   // RNE to bf16
  return (unsigned short)(u >> 16);
}

static __device__ __forceinline__ f32x4 mfma32(bf16x8 a, bf16x8 b, f32x4 c) {
  return __builtin_amdgcn_mfma_f32_16x16x32_bf16(a, b, c, 0, 0, 0);
}
static __device__ __forceinline__ f32x4 mfma16(s16x4 a, s16x4 b, f32x4 c) {
#if __has_builtin(__builtin_amdgcn_mfma_f32_16x16x16bf16_1k)
  return __builtin_amdgcn_mfma_f32_16x16x16bf16_1k(a, b, c, 0, 0, 0);
#else
  asm("v_mfma_f32_16x16x16_bf16 %0, %1, %2, %0" : "+v"(c) : "v"(a), "v"(b));
  return c;
#endif
}

// hardware transpose read: lane l elem j <- lds[base + (l&15) + j*16 + (l>>4)*64] (bf16 elems)
template <int OFF>
static __device__ __forceinline__ s16x4 tr16(unsigned addr) {
  s16x4 r;
  asm volatile("ds_read_b64_tr_b16 %0, %1 offset:%2" : "=v"(r) : "v"(addr), "i"(OFF));
  return r;
}

// ---------------- weight packing ----------------

__global__ __launch_bounds__(256) void pack_qkv(
    const float* __restrict__ wq, const float* __restrict__ wk, const float* __restrict__ wv,
    unsigned short* __restrict__ outW)  // [3072][1024], row n = proj*1024 + h*64 + e, col = d
{
  __shared__ float tile[64][65];
  const int blk = blockIdx.x;       // 768 = 16 dchunk x 16 h x 3 proj
  const int dc = blk & 15;
  const int h  = (blk >> 4) & 15;
  const int p  = blk >> 8;
  const float* w = p == 0 ? wq : (p == 1 ? wk : wv);
  const int tid = threadIdx.x;
#pragma unroll
  for (int i = 0; i < 4; ++i) {
    int idx = i * 256 + tid;
    int dl = idx >> 4;
    int e0 = (idx & 15) * 4;
    const float4 v = *(const float4*)&w[(size_t)(h * 1024 + dc * 64 + dl) * 64 + e0];
    tile[dl][e0 + 0] = v.x; tile[dl][e0 + 1] = v.y;
    tile[dl][e0 + 2] = v.z; tile[dl][e0 + 3] = v.w;
  }
  __syncthreads();
#pragma unroll
  for (int i = 0; i < 4; ++i) {
    int idx = i * 256 + tid;
    int e = idx >> 4;
    int d0 = (idx & 15) * 4;
    ushort4 o;
    o.x = f2bu(tile[d0 + 0][e]); o.y = f2bu(tile[d0 + 1][e]);
    o.z = f2bu(tile[d0 + 2][e]); o.w = f2bu(tile[d0 + 3][e]);
    *(ushort4*)&outW[(size_t)(p * 1024 + h * 64 + e) * 1024 + dc * 64 + d0] = o;
  }
}

__global__ __launch_bounds__(256) void transpose_f32_to_bf16(
    const float* __restrict__ in, unsigned short* __restrict__ out, int R, int C)
{ // in [R][C] fp32 -> out [C][R] bf16
  __shared__ float tile[32][33];
  int c0 = blockIdx.x * 32, r0 = blockIdx.y * 32;
  int x = threadIdx.x, y = threadIdx.y;
#pragma unroll
  for (int i = 0; i < 32; i += 8)
    tile[y + i][x] = in[(size_t)(r0 + y + i) * C + c0 + x];
  __syncthreads();
#pragma unroll
  for (int i = 0; i < 32; i += 8)
    out[(size_t)(c0 + y + i) * R + r0 + x] = f2bu(tile[x][y + i]);
}

// ---------------- layernorm ----------------

__global__ __launch_bounds__(256) void ln_kernel(
    const float* __restrict__ x, const float* __restrict__ gamma, const float* __restrict__ beta,
    unsigned short* __restrict__ outH)
{
  const int row = blockIdx.x;
  const int tid = threadIdx.x;
  const float4 v = ((const float4*)(x + (size_t)row * Dz))[tid];
  float s = v.x + v.y + v.z + v.w;
  float s2 = v.x * v.x + v.y * v.y + v.z * v.z + v.w * v.w;
#pragma unroll
  for (int o = 32; o > 0; o >>= 1) {
    s += __shfl_xor(s, o);
    s2 += __shfl_xor(s2, o);
  }
  __shared__ float ss[4], ss2[4];
  if ((tid & 63) == 0) { ss[tid >> 6] = s; ss2[tid >> 6] = s2; }
  __syncthreads();
  s = ss[0] + ss[1] + ss[2] + ss[3];
  s2 = ss2[0] + ss2[1] + ss2[2] + ss2[3];
  const float mean = s * (1.0f / Dz);
  const float rstd = rsqrtf(s2 * (1.0f / Dz) - mean * mean + 1e-5f);
  const float4 g4 = ((const float4*)gamma)[tid];
  const float4 b4 = ((const float4*)beta)[tid];
  ushort4 o;
  o.x = f2bu((v.x - mean) * rstd * g4.x + b4.x);
  o.y = f2bu((v.y - mean) * rstd * g4.y + b4.y);
  o.z = f2bu((v.z - mean) * rstd * g4.z + b4.z);
  o.w = f2bu((v.w - mean) * rstd * g4.w + b4.w);
  ((ushort4*)(outH + (size_t)row * Dz))[tid] = o;
}

// ---------------- GEMM m97-structure: 128x128, BK=64, 256 thr / 4 waves, 4 blk/CU ----
// (R14-exact, best measured: total 421us.)
// Single-buffered, plain __syncthreads staging (m99/m100), unpinned compute
// (m141/R9), (row&7)/128B-span XOR swizzle (0 conflicts), bijective XCD swizzle.

enum { EPI_BF16 = 0, EPI_GELU_BF16 = 1, EPI_RES_F32 = 2, EPI_BIAS_RES_F32 = 3 };

template <int EPI>
__global__ __launch_bounds__(256, 4) void gemm128(
    const unsigned short* __restrict__ A,   // [M,K] bf16
    const unsigned short* __restrict__ BT,  // [N,K] bf16
    int M, int N, int K,
    const float* bias, const float* resid,  // resid/outf may alias: no __restrict__
    unsigned short* outb, float* outf)
{
  constexpr int BK = 64;
  __shared__ unsigned short As[128 * BK];  // [row][64k], 16B chunks, (row&7) XOR
  __shared__ unsigned short Bs[128 * BK];
  const int tid = threadIdx.x;
  const int lane = tid & 63;
  const int wid = tid >> 6;
  const int wm = (wid >> 1) * 64;
  const int wn = (wid & 1) * 64;
  const int rsel = lane & 15;
  const int kgrp = lane >> 4;

  // XCD-chunked bijective swizzle (nwg % 8 == 0 for all our grids)
  const int nwg = gridDim.x;
  const int bid = blockIdx.x;
  const int id2 = (bid & 7) * (nwg >> 3) + (bid >> 3);
  const int nbx = N / 128;
  const int n0 = (id2 % nbx) * 128;
  const int m0 = (id2 / nbx) * 128;

  f32x4 acc[4][4] = {};

  const int T = K >> 6;
  for (int t = 0; t < T; ++t) {
    if (t) __syncthreads();
    const int kOff = t * BK;
#pragma unroll
    for (int r = 0; r < 4; ++r) {          // 1024 chunks of 16B per matrix tile
      int gc = r * 256 + tid;
      int row = gc >> 3;
      int kcs = (gc & 7) ^ (row & 7);      // proven 128B-span swizzle (0 conflicts)
      GLOAD_LDS16(A + (size_t)(m0 + row) * K + kOff + kcs * 8, &As[gc * 8]);
      GLOAD_LDS16(BT + (size_t)(n0 + row) * K + kOff + kcs * 8, &Bs[gc * 8]);
    }
    __syncthreads();
#pragma unroll
    for (int kk = 0; kk < 2; ++kk) {
      bf16x8 af[4], bfr[4];
#pragma unroll
      for (int mf = 0; mf < 4; ++mf) {
        int ar = wm + mf * 16 + rsel;
        af[mf] = *(const bf16x8*)&As[ar * BK + (((kk * 4 + kgrp) ^ (ar & 7)) * 8)];
      }
#pragma unroll
      for (int nf = 0; nf < 4; ++nf) {
        int br = wn + nf * 16 + rsel;
        bfr[nf] = *(const bf16x8*)&Bs[br * BK + (((kk * 4 + kgrp) ^ (br & 7)) * 8)];
      }
      // unpinned: compiler emits fine-grained lgkmcnt and co-schedules with MFMA
#pragma unroll
      for (int mf = 0; mf < 4; ++mf)
#pragma unroll
        for (int nf = 0; nf < 4; ++nf)
          acc[mf][nf] = mfma32(af[mf], bfr[nf], acc[mf][nf]);
    }
  }

#pragma unroll
  for (int mf = 0; mf < 4; ++mf) {
#pragma unroll
    for (int nf = 0; nf < 4; ++nf) {
      const int n = n0 + wn + nf * 16 + rsel;
#pragma unroll
      for (int j = 0; j < 4; ++j) {
        const int m = m0 + wm + mf * 16 + kgrp * 4 + j;
        const size_t idx = (size_t)m * N + n;
        float v = acc[mf][nf][j];
        if constexpr (EPI == EPI_BF16) {
          outb[idx] = f2bu(v);
        } else if constexpr (EPI == EPI_GELU_BF16) {
          v += bias[n];
          v = 0.5f * v * (1.0f + erff(v * 0.70710678118654752f));
          outb[idx] = f2bu(v);
        } else if constexpr (EPI == EPI_RES_F32) {
          outf[idx] = v + resid[idx];
        } else {
          outf[idx] = v + bias[n] + resid[idx];
        }
      }
    }
  }
}

// ---------------- fused causal flash attention (R14 + FMA-fold only) ----------------
// R15 post-mortem: bundled {FMA-fold, ones-MFMA l} regressed via +29MB FETCH —
// the ones-MFMA region skewed paired-block progress and broke K/V L2 co-timing.
// This round: R14-exact structure (lrun/psum/shuffles restored), ONLY the fold:
// mask/max in raw-score domain, scale once post-reduce, p = exp2(fma(sc,SCL,-m))
// (-16 v_mul per proc, no phase-structure change).

__global__ __launch_bounds__(256, 4) void attn_kernel(
    const unsigned short* __restrict__ QKV,  // [Mz][3072] bf16 (q|k|v, feature h*64+e)
    unsigned short* __restrict__ outA)       // [Mz][Dz]  bf16
{
  __shared__ unsigned short Kt[64 * 64];  // [key][d], 16B d-chunk XOR-swizzled by key&7
  __shared__ unsigned short Vs[64 * 64];  // subtiled for tr16 reads
  const int pi = blockIdx.x;  // 0..15
  const int hh = blockIdx.y;
  const int bb = blockIdx.z;
  const int tid = threadIdx.x;
  const int lane = tid & 63;
  const int w = tid >> 6;
  const int rsel = lane & 15;
  const int kgrp = lane >> 4;
  const int qt[2] = {pi, 31 - pi};

  bf16x8 qf0[2], qf1[2];
  int qg[2];
#pragma unroll
  for (int s = 0; s < 2; ++s) {
    qg[s] = qt[s] * 64 + w * 16 + rsel;
    const size_t rowQ = (size_t)(bb * Sz + qg[s]) * 3072 + hh * 64;
    qf0[s] = *(const bf16x8*)&QKV[rowQ + kgrp * 8];
    qf1[s] = *(const bf16x8*)&QKV[rowQ + 32 + kgrp * 8];
  }

  f32x4 accO[2][4] = {};  // [set][df]; O^T row=d=(df*16+kgrp*4+j), col=q=rsel
  float mr[2] = {-INFINITY, -INFINITY};
  float lr[2] = {0.0f, 0.0f};

  auto vs3 = (__attribute__((address_space(3))) unsigned short*)Vs;
  const unsigned vbase = (unsigned)(uintptr_t)vs3 + (unsigned)lane * 8u;
  constexpr float SCL = 0.18033688011112042f;  // log2(e)/sqrt(64)

  // S^T + online softmax -> P^T bf16 B-frags. Raw-domain max; FMA-folded exp arg.
  auto proc = [&](const bf16x8& q0, const bf16x8& q1, float& mrun, float& lrun,
                  f32x4* accS, s16x4* pb, bool edge, int qgs, int kb) {
    f32x4 sc[4];
    __builtin_amdgcn_s_setprio(1);
#pragma unroll
    for (int kf = 0; kf < 4; ++kf) {
      int key = kf * 16 + rsel;
      bf16x8 k0 = *(const bf16x8*)&Kt[key * 64 + ((kgrp ^ (key & 7)) * 8)];
      bf16x8 k1 = *(const bf16x8*)&Kt[key * 64 + (((4 + kgrp) ^ (key & 7)) * 8)];
      f32x4 s = {};
      s = mfma32(k0, q0, s);
      s = mfma32(k1, q1, s);
      sc[kf] = s;
    }
    __builtin_amdgcn_s_setprio(0);
    float tmax = -INFINITY;
#pragma unroll
    for (int kf = 0; kf < 4; ++kf)
#pragma unroll
      for (int j = 0; j < 4; ++j) {
        if (edge) {
          int keyg = kb + kf * 16 + kgrp * 4 + j;
          if (keyg > qgs) sc[kf][j] = -INFINITY;
        }
        tmax = fmaxf(tmax, sc[kf][j]);
      }
    tmax = fmaxf(tmax, __shfl_xor(tmax, 16));
    tmax = fmaxf(tmax, __shfl_xor(tmax, 32));
    const float tmaxs = tmax * SCL;   // scale once, after the reduce
    // defer-rescale (T13): skip O/l rescale while max growth stays under 8 (log2 units)
    if (!__all(tmaxs <= mrun + 8.0f)) {
      const float mnew = fmaxf(mrun, tmaxs);
      const float corr = exp2f(mrun - mnew);
      lrun *= corr;
#pragma unroll
      for (int df = 0; df < 4; ++df) accS[df] *= corr;
      mrun = mnew;
    }
    float psum = 0.0f;
#pragma unroll
    for (int kf = 0; kf < 4; ++kf) {
      bf16x4 pv;
#pragma unroll
      for (int j = 0; j < 4; ++j) {
        float e = exp2f(fmaf(sc[kf][j], SCL, -mrun));  // one v_fma + v_exp
        psum += e;
        pv[j] = (__bf16)e;  // v_cvt_pk_bf16_f32 pairs
      }
      pb[kf] = __builtin_bit_cast(s16x4, pv);
    }
    psum += __shfl_xor(psum, 16);
    psum += __shfl_xor(psum, 32);
    lrun += psum;
  };

  for (int kt = 0; kt <= qt[1]; ++kt) {
    const int kb = kt * 64;
    if (kt) __syncthreads();  // prev tile's LDS reads done before overwrite
    // stage K: LDS linear, global d-chunk XOR-swizzled by key&7
#pragma unroll
    for (int r = 0; r < 2; ++r) {
      int c = r * 256 + tid;
      int key = c >> 3;
      int dcs = (c & 7) ^ (key & 7);
      GLOAD_LDS16(QKV + (size_t)(bb * Sz + kb + key) * 3072 + 1024 + hh * 64 + dcs * 8,
                  &Kt[c * 8]);
    }
    // stage V: LDS linear; source permuted so LDS holds subtiled layout
#pragma unroll
    for (int r = 0; r < 2; ++r) {
      int c = r * 256 + tid;
      int key = ((c >> 3) & 15) * 4 + ((c >> 1) & 3);
      int d = (c >> 7) * 16 + (c & 1) * 8;
      GLOAD_LDS16(QKV + (size_t)(bb * Sz + kb + key) * 3072 + 2048 + hh * 64 + d,
                  &Vs[c * 8]);
    }
    __syncthreads();

    s16x4 pb[2][4];
#pragma unroll
    for (int s = 0; s < 2; ++s)
      if (kt <= qt[s])
        proc(qf0[s], qf1[s], mr[s], lr[s], accO[s], pb[s], kt == qt[s], qg[s], kb);

    // O^T += V^T @ P^T — V-frags shared by both q-sets
#pragma unroll
    for (int df = 0; df < 4; ++df) {
      unsigned a = vbase + df * 2048;
      s16x4 vf0 = tr16<0>(a);
      s16x4 vf1 = tr16<512>(a);
      s16x4 vf2 = tr16<1024>(a);
      s16x4 vf3 = tr16<1536>(a);
      asm volatile("s_waitcnt lgkmcnt(0)" ::: "memory");
      __builtin_amdgcn_sched_barrier(0);
      __builtin_amdgcn_s_setprio(1);
#pragma unroll
      for (int s = 0; s < 2; ++s) {
        if (kt <= qt[s]) {
          accO[s][df] = mfma16(vf0, pb[s][0], accO[s][df]);
          accO[s][df] = mfma16(vf1, pb[s][1], accO[s][df]);
          accO[s][df] = mfma16(vf2, pb[s][2], accO[s][df]);
          accO[s][df] = mfma16(vf3, pb[s][3], accO[s][df]);
        }
      }
      __builtin_amdgcn_s_setprio(0);
    }
  }

#pragma unroll
  for (int s = 0; s < 2; ++s) {
    const float rl = 1.0f / lr[s];
    const size_t orow = (size_t)(bb * Sz + qg[s]) * Dz + hh * 64;
#pragma unroll
    for (int df = 0; df < 4; ++df) {
      s16x4 o;
#pragma unroll
      for (int j = 0; j < 4; ++j) o[j] = (short)f2bu(accO[s][df][j] * rl);
      *(s16x4*)&outA[orow + df * 16 + kgrp * 4] = o;
    }
  }
}

// ---------------- launch ----------------

extern "C" void kernel_launch(void* const* d_in, const int* in_sizes, int n_in,
                              void* d_out, int out_size, void* d_ws, size_t ws_size,
                              hipStream_t stream) {
  const float* x   = (const float*)d_in[0];
  // d_in[1] = mask (causal, known) — unused
  const float* wq  = (const float*)d_in[2];
  const float* wk  = (const float*)d_in[3];
  const float* wv  = (const float*)d_in[4];
  const float* wo  = (const float*)d_in[5];
  const float* w1  = (const float*)d_in[6];
  const float* b1  = (const float*)d_in[7];
  const float* w2  = (const float*)d_in[8];
  const float* b2  = (const float*)d_in[9];
  const float* g1  = (const float*)d_in[10];
  const float* be1 = (const float*)d_in[11];
  const float* g2  = (const float*)d_in[12];
  const float* be2 = (const float*)d_in[13];
  float* out = (float*)d_out;

  char* ws = (char*)d_ws;
  unsigned short* WqkvT = (unsigned short*)(ws);
  unsigned short* WoT   = (unsigned short*)(ws + 6291456);
  unsigned short* W1T   = (unsigned short*)(ws + 8388608);
  unsigned short* W2T   = (unsigned short*)(ws + 16777216);
  unsigned short* hbuf  = (unsigned short*)(ws + 25165824);
  unsigned short* big   = (unsigned short*)(ws + 41943040);  // QKV, later ff1

  dim3 tb(32, 8);
  pack_qkv<<<768, 256, 0, stream>>>(wq, wk, wv, WqkvT);
  transpose_f32_to_bf16<<<dim3(32, 32), tb, 0, stream>>>(wo, WoT, 1024, 1024);
  transpose_f32_to_bf16<<<dim3(128, 32), tb, 0, stream>>>(w1, W1T, 1024, 4096);
  transpose_f32_to_bf16<<<dim3(32, 128), tb, 0, stream>>>(w2, W2T, 4096, 1024);

  ln_kernel<<<Mz, 256, 0, stream>>>(x, g1, be1, hbuf);
  gemm128<EPI_BF16><<<1536, 256, 0, stream>>>(
      hbuf, WqkvT, Mz, 3072, 1024, nullptr, nullptr, big, nullptr);
  attn_kernel<<<dim3(16, 16, 4), 256, 0, stream>>>(big, hbuf);
  gemm128<EPI_RES_F32><<<512, 256, 0, stream>>>(
      hbuf, WoT, Mz, 1024, 1024, nullptr, x, nullptr, out);
  ln_kernel<<<Mz, 256, 0, stream>>>(out, g2, be2, hbuf);
  gemm128<EPI_GELU_BF16><<<2048, 256, 0, stream>>>(
      hbuf, W1T, Mz, Fz, 1024, b1, nullptr, big, nullptr);
  gemm128<EPI_BIAS_RES_F32><<<512, 256, 0, stream>>>(
      big, W2T, Mz, 1024, Fz, b2, out, nullptr, out);
}

// Round 17
// 415.323 us; speedup vs baseline: 1.0529x; 1.0144x over previous
//
#include <hip/hip_runtime.h>
#include <hip/hip_bf16.h>
#include <math.h>

// GPT decoder layer, MI355X/gfx950. bf16 MFMA GEMMs + fused flash attention.
// B=4 S=2048 D=1024 H=16 DH=64 F=4096.  Workspace layout (bytes):
//   [0,6M)      WqkvT  bf16 [3072][1024]   (pre-transposed, k-contiguous)
//   [6M,8M)     WoT    bf16 [1024][1024]
//   [8M,16M)    W1T    bf16 [4096][1024]
//   [16M,24M)   W2T    bf16 [1024][4096]
//   [24M,40M)   hbuf   bf16 [8192][1024]   (h -> attn_out -> h2, reused)
//   [40M,104M)  big    bf16                (QKV [8192][3072], later ff1 [8192][4096])

#define Bz 4
#define Sz 2048
#define Dz 1024
#define Hz 16
#define DHz 64
#define Fz 4096
#define Mz 8192

typedef float f32x4 __attribute__((ext_vector_type(4)));
typedef __bf16 bf16x8 __attribute__((ext_vector_type(8)));
typedef __bf16 bf16x4 __attribute__((ext_vector_type(4)));
typedef short s16x4 __attribute__((ext_vector_type(4)));

#define GLOAD_LDS16(g, l)                                                                   \
  __builtin_amdgcn_global_load_lds((const __attribute__((address_space(1))) unsigned int*)(g), \
                                   (__attribute__((address_space(3))) unsigned int*)(l), 16, 0, 0)

static __device__ __forceinline__ unsigned short f2bu(float f) {
  unsigned int u = __float_as_uint(f);
  u += 0x7fffu + ((u >> 16) & 1u);   // RNE to bf16
  return (unsigned short)(u >> 16);
}

static __device__ __forceinline__ f32x4 mfma32(bf16x8 a, bf16x8 b, f32x4 c) {
  return __builtin_amdgcn_mfma_f32_16x16x32_bf16(a, b, c, 0, 0, 0);
}
static __device__ __forceinline__ f32x4 mfma16(s16x4 a, s16x4 b, f32x4 c) {
#if __has_builtin(__builtin_amdgcn_mfma_f32_16x16x16bf16_1k)
  return __builtin_amdgcn_mfma_f32_16x16x16bf16_1k(a, b, c, 0, 0, 0);
#else
  asm("v_mfma_f32_16x16x16_bf16 %0, %1, %2, %0" : "+v"(c) : "v"(a), "v"(b));
  return c;
#endif
}

// hardware transpose read: lane l elem j <- lds[base + (l&15) + j*16 + (l>>4)*64] (bf16 elems)
template <int OFF>
static __device__ __forceinline__ s16x4 tr16(unsigned addr) {
  s16x4 r;
  asm volatile("ds_read_b64_tr_b16 %0, %1 offset:%2" : "=v"(r) : "v"(addr), "i"(OFF));
  return r;
}

// erf via Abramowitz-Stegun 7.1.26 (max |err| 1.5e-7 -- exact at bf16 output
// precision). ~13 VALU ops vs ~40 for the ocml erff libcall (both branches
// execute under divergence). v_rcp (1ulp) + native exp2.
static __device__ __forceinline__ float erf_fast(float x) {
  float ax = fabsf(x);
  float t = __builtin_amdgcn_rcpf(fmaf(0.3275911f, ax, 1.0f));
  float poly = fmaf(fmaf(fmaf(fmaf(1.061405429f, t, -1.453152027f),
                              t, 1.421413741f),
                         t, -0.284496736f),
                    t, 0.254829592f) * t;
  float e = exp2f(ax * ax * -1.4426950408889634f);
  float er = fmaf(-poly, e, 1.0f);
  return copysignf(er, x);
}

// ---------------- weight packing ----------------

__global__ __launch_bounds__(256) void pack_qkv(
    const float* __restrict__ wq, const float* __restrict__ wk, const float* __restrict__ wv,
    unsigned short* __restrict__ outW)  // [3072][1024], row n = proj*1024 + h*64 + e, col = d
{
  __shared__ float tile[64][65];
  const int blk = blockIdx.x;       // 768 = 16 dchunk x 16 h x 3 proj
  const int dc = blk & 15;
  const int h  = (blk >> 4) & 15;
  const int p  = blk >> 8;
  const float* w = p == 0 ? wq : (p == 1 ? wk : wv);
  const int tid = threadIdx.x;
#pragma unroll
  for (int i = 0; i < 4; ++i) {
    int idx = i * 256 + tid;
    int dl = idx >> 4;
    int e0 = (idx & 15) * 4;
    const float4 v = *(const float4*)&w[(size_t)(h * 1024 + dc * 64 + dl) * 64 + e0];
    tile[dl][e0 + 0] = v.x; tile[dl][e0 + 1] = v.y;
    tile[dl][e0 + 2] = v.z; tile[dl][e0 + 3] = v.w;
  }
  __syncthreads();
#pragma unroll
  for (int i = 0; i < 4; ++i) {
    int idx = i * 256 + tid;
    int e = idx >> 4;
    int d0 = (idx & 15) * 4;
    ushort4 o;
    o.x = f2bu(tile[d0 + 0][e]); o.y = f2bu(tile[d0 + 1][e]);
    o.z = f2bu(tile[d0 + 2][e]); o.w = f2bu(tile[d0 + 3][e]);
    *(ushort4*)&outW[(size_t)(p * 1024 + h * 64 + e) * 1024 + dc * 64 + d0] = o;
  }
}

__global__ __launch_bounds__(256) void transpose_f32_to_bf16(
    const float* __restrict__ in, unsigned short* __restrict__ out, int R, int C)
{ // in [R][C] fp32 -> out [C][R] bf16
  __shared__ float tile[32][33];
  int c0 = blockIdx.x * 32, r0 = blockIdx.y * 32;
  int x = threadIdx.x, y = threadIdx.y;
#pragma unroll
  for (int i = 0; i < 32; i += 8)
    tile[y + i][x] = in[(size_t)(r0 + y + i) * C + c0 + x];
  __syncthreads();
#pragma unroll
  for (int i = 0; i < 32; i += 8)
    out[(size_t)(c0 + y + i) * R + r0 + x] = f2bu(tile[x][y + i]);
}

// ---------------- layernorm ----------------

__global__ __launch_bounds__(256) void ln_kernel(
    const float* __restrict__ x, const float* __restrict__ gamma, const float* __restrict__ beta,
    unsigned short* __restrict__ outH)
{
  const int row = blockIdx.x;
  const int tid = threadIdx.x;
  const float4 v = ((const float4*)(x + (size_t)row * Dz))[tid];
  float s = v.x + v.y + v.z + v.w;
  float s2 = v.x * v.x + v.y * v.y + v.z * v.z + v.w * v.w;
#pragma unroll
  for (int o = 32; o > 0; o >>= 1) {
    s += __shfl_xor(s, o);
    s2 += __shfl_xor(s2, o);
  }
  __shared__ float ss[4], ss2[4];
  if ((tid & 63) == 0) { ss[tid >> 6] = s; ss2[tid >> 6] = s2; }
  __syncthreads();
  s = ss[0] + ss[1] + ss[2] + ss[3];
  s2 = ss2[0] + ss2[1] + ss2[2] + ss2[3];
  const float mean = s * (1.0f / Dz);
  const float rstd = rsqrtf(s2 * (1.0f / Dz) - mean * mean + 1e-5f);
  const float4 g4 = ((const float4*)gamma)[tid];
  const float4 b4 = ((const float4*)beta)[tid];
  ushort4 o;
  o.x = f2bu((v.x - mean) * rstd * g4.x + b4.x);
  o.y = f2bu((v.y - mean) * rstd * g4.y + b4.y);
  o.z = f2bu((v.z - mean) * rstd * g4.z + b4.z);
  o.w = f2bu((v.w - mean) * rstd * g4.w + b4.w);
  ((ushort4*)(outH + (size_t)row * Dz))[tid] = o;
}

// ---------------- GEMM m97-structure: 128x128, BK=64, 256 thr / 4 waves, 4 blk/CU ----
// (R14-exact structure, best measured: total 421us.)
// Single-buffered, plain __syncthreads staging (m99/m100), unpinned compute
// (m141/R9), (row&7)/128B-span XOR swizzle (0 conflicts), bijective XCD swizzle.
// R17 change: GELU epilogue uses erf_fast (A&S 7.1.26) instead of the erff
// libcall (-~27 VALU/element x 64 elements/thread epilogue tail on FFN1).

enum { EPI_BF16 = 0, EPI_GELU_BF16 = 1, EPI_RES_F32 = 2, EPI_BIAS_RES_F32 = 3 };

template <int EPI>
__global__ __launch_bounds__(256, 4) void gemm128(
    const unsigned short* __restrict__ A,   // [M,K] bf16
    const unsigned short* __restrict__ BT,  // [N,K] bf16
    int M, int N, int K,
    const float* bias, const float* resid,  // resid/outf may alias: no __restrict__
    unsigned short* outb, float* outf)
{
  constexpr int BK = 64;
  __shared__ unsigned short As[128 * BK];  // [row][64k], 16B chunks, (row&7) XOR
  __shared__ unsigned short Bs[128 * BK];
  const int tid = threadIdx.x;
  const int lane = tid & 63;
  const int wid = tid >> 6;
  const int wm = (wid >> 1) * 64;
  const int wn = (wid & 1) * 64;
  const int rsel = lane & 15;
  const int kgrp = lane >> 4;

  // XCD-chunked bijective swizzle (nwg % 8 == 0 for all our grids)
  const int nwg = gridDim.x;
  const int bid = blockIdx.x;
  const int id2 = (bid & 7) * (nwg >> 3) + (bid >> 3);
  const int nbx = N / 128;
  const int n0 = (id2 % nbx) * 128;
  const int m0 = (id2 / nbx) * 128;

  f32x4 acc[4][4] = {};

  const int T = K >> 6;
  for (int t = 0; t < T; ++t) {
    if (t) __syncthreads();
    const int kOff = t * BK;
#pragma unroll
    for (int r = 0; r < 4; ++r) {          // 1024 chunks of 16B per matrix tile
      int gc = r * 256 + tid;
      int row = gc >> 3;
      int kcs = (gc & 7) ^ (row & 7);      // proven 128B-span swizzle (0 conflicts)
      GLOAD_LDS16(A + (size_t)(m0 + row) * K + kOff + kcs * 8, &As[gc * 8]);
      GLOAD_LDS16(BT + (size_t)(n0 + row) * K + kOff + kcs * 8, &Bs[gc * 8]);
    }
    __syncthreads();
#pragma unroll
    for (int kk = 0; kk < 2; ++kk) {
      bf16x8 af[4], bfr[4];
#pragma unroll
      for (int mf = 0; mf < 4; ++mf) {
        int ar = wm + mf * 16 + rsel;
        af[mf] = *(const bf16x8*)&As[ar * BK + (((kk * 4 + kgrp) ^ (ar & 7)) * 8)];
      }
#pragma unroll
      for (int nf = 0; nf < 4; ++nf) {
        int br = wn + nf * 16 + rsel;
        bfr[nf] = *(const bf16x8*)&Bs[br * BK + (((kk * 4 + kgrp) ^ (br & 7)) * 8)];
      }
      // unpinned: compiler emits fine-grained lgkmcnt and co-schedules with MFMA
#pragma unroll
      for (int mf = 0; mf < 4; ++mf)
#pragma unroll
        for (int nf = 0; nf < 4; ++nf)
          acc[mf][nf] = mfma32(af[mf], bfr[nf], acc[mf][nf]);
    }
  }

#pragma unroll
  for (int mf = 0; mf < 4; ++mf) {
#pragma unroll
    for (int nf = 0; nf < 4; ++nf) {
      const int n = n0 + wn + nf * 16 + rsel;
#pragma unroll
      for (int j = 0; j < 4; ++j) {
        const int m = m0 + wm + mf * 16 + kgrp * 4 + j;
        const size_t idx = (size_t)m * N + n;
        float v = acc[mf][nf][j];
        if constexpr (EPI == EPI_BF16) {
          outb[idx] = f2bu(v);
        } else if constexpr (EPI == EPI_GELU_BF16) {
          v += bias[n];
          v = 0.5f * v * (1.0f + erf_fast(v * 0.70710678118654752f));
          outb[idx] = f2bu(v);
        } else if constexpr (EPI == EPI_RES_F32) {
          outf[idx] = v + resid[idx];
        } else {
          outf[idx] = v + bias[n] + resid[idx];
        }
      }
    }
  }
}

// ---------------- fused causal flash attention (R16-exact: R14 + FMA-fold) ----------
// Block = PAIR of q-tiles {i, 31-i} x head x batch, grid 1024 = 4 blocks/CU.
// S^T = K @ Q^T via mfma 16x16x32; P^T stays in registers as the B-frag of
// mfma 16x16x16 for O^T = V^T @ P^T; V read with ds_read_b64_tr_b16, V-frags
// shared by both q-sets. Softmax in log2 domain with defer-rescale (THR=8);
// mask/max in raw-score domain, p = exp2(fma(sc, SCL, -m)).
// NOTE: loop-body perturbations (R12 dbuf, R15 ones-MFMA) both regressed via
// broken K/V L2 co-timing of paired blocks (+25-30MB FETCH) -- do not perturb.

__global__ __launch_bounds__(256, 4) void attn_kernel(
    const unsigned short* __restrict__ QKV,  // [Mz][3072] bf16 (q|k|v, feature h*64+e)
    unsigned short* __restrict__ outA)       // [Mz][Dz]  bf16
{
  __shared__ unsigned short Kt[64 * 64];  // [key][d], 16B d-chunk XOR-swizzled by key&7
  __shared__ unsigned short Vs[64 * 64];  // subtiled for tr16 reads
  const int pi = blockIdx.x;  // 0..15
  const int hh = blockIdx.y;
  const int bb = blockIdx.z;
  const int tid = threadIdx.x;
  const int lane = tid & 63;
  const int w = tid >> 6;
  const int rsel = lane & 15;
  const int kgrp = lane >> 4;
  const int qt[2] = {pi, 31 - pi};

  bf16x8 qf0[2], qf1[2];
  int qg[2];
#pragma unroll
  for (int s = 0; s < 2; ++s) {
    qg[s] = qt[s] * 64 + w * 16 + rsel;
    const size_t rowQ = (size_t)(bb * Sz + qg[s]) * 3072 + hh * 64;
    qf0[s] = *(const bf16x8*)&QKV[rowQ + kgrp * 8];
    qf1[s] = *(const bf16x8*)&QKV[rowQ + 32 + kgrp * 8];
  }

  f32x4 accO[2][4] = {};  // [set][df]; O^T row=d=(df*16+kgrp*4+j), col=q=rsel
  float mr[2] = {-INFINITY, -INFINITY};
  float lr[2] = {0.0f, 0.0f};

  auto vs3 = (__attribute__((address_space(3))) unsigned short*)Vs;
  const unsigned vbase = (unsigned)(uintptr_t)vs3 + (unsigned)lane * 8u;
  constexpr float SCL = 0.18033688011112042f;  // log2(e)/sqrt(64)

  // S^T + online softmax -> P^T bf16 B-frags. Raw-domain max; FMA-folded exp arg.
  auto proc = [&](const bf16x8& q0, const bf16x8& q1, float& mrun, float& lrun,
                  f32x4* accS, s16x4* pb, bool edge, int qgs, int kb) {
    f32x4 sc[4];
    __builtin_amdgcn_s_setprio(1);
#pragma unroll
    for (int kf = 0; kf < 4; ++kf) {
      int key = kf * 16 + rsel;
      bf16x8 k0 = *(const bf16x8*)&Kt[key * 64 + ((kgrp ^ (key & 7)) * 8)];
      bf16x8 k1 = *(const bf16x8*)&Kt[key * 64 + (((4 + kgrp) ^ (key & 7)) * 8)];
      f32x4 s = {};
      s = mfma32(k0, q0, s);
      s = mfma32(k1, q1, s);
      sc[kf] = s;
    }
    __builtin_amdgcn_s_setprio(0);
    float tmax = -INFINITY;
#pragma unroll
    for (int kf = 0; kf < 4; ++kf)
#pragma unroll
      for (int j = 0; j < 4; ++j) {
        if (edge) {
          int keyg = kb + kf * 16 + kgrp * 4 + j;
          if (keyg > qgs) sc[kf][j] = -INFINITY;
        }
        tmax = fmaxf(tmax, sc[kf][j]);
      }
    tmax = fmaxf(tmax, __shfl_xor(tmax, 16));
    tmax = fmaxf(tmax, __shfl_xor(tmax, 32));
    const float tmaxs = tmax * SCL;   // scale once, after the reduce
    // defer-rescale (T13): skip O/l rescale while max growth stays under 8 (log2 units)
    if (!__all(tmaxs <= mrun + 8.0f)) {
      const float mnew = fmaxf(mrun, tmaxs);
      const float corr = exp2f(mrun - mnew);
      lrun *= corr;
#pragma unroll
      for (int df = 0; df < 4; ++df) accS[df] *= corr;
      mrun = mnew;
    }
    float psum = 0.0f;
#pragma unroll
    for (int kf = 0; kf < 4; ++kf) {
      bf16x4 pv;
#pragma unroll
      for (int j = 0; j < 4; ++j) {
        float e = exp2f(fmaf(sc[kf][j], SCL, -mrun));  // one v_fma + v_exp
        psum += e;
        pv[j] = (__bf16)e;  // v_cvt_pk_bf16_f32 pairs
      }
      pb[kf] = __builtin_bit_cast(s16x4, pv);
    }
    psum += __shfl_xor(psum, 16);
    psum += __shfl_xor(psum, 32);
    lrun += psum;
  };

  for (int kt = 0; kt <= qt[1]; ++kt) {
    const int kb = kt * 64;
    if (kt) __syncthreads();  // prev tile's LDS reads done before overwrite
    // stage K: LDS linear, global d-chunk XOR-swizzled by key&7
#pragma unroll
    for (int r = 0; r < 2; ++r) {
      int c = r * 256 + tid;
      int key = c >> 3;
      int dcs = (c & 7) ^ (key & 7);
      GLOAD_LDS16(QKV + (size_t)(bb * Sz + kb + key) * 3072 + 1024 + hh * 64 + dcs * 8,
                  &Kt[c * 8]);
    }
    // stage V: LDS linear; source permuted so LDS holds subtiled layout
#pragma unroll
    for (int r = 0; r < 2; ++r) {
      int c = r * 256 + tid;
      int key = ((c >> 3) & 15) * 4 + ((c >> 1) & 3);
      int d = (c >> 7) * 16 + (c & 1) * 8;
      GLOAD_LDS16(QKV + (size_t)(bb * Sz + kb + key) * 3072 + 2048 + hh * 64 + d,
                  &Vs[c * 8]);
    }
    __syncthreads();

    s16x4 pb[2][4];
#pragma unroll
    for (int s = 0; s < 2; ++s)
      if (kt <= qt[s])
        proc(qf0[s], qf1[s], mr[s], lr[s], accO[s], pb[s], kt == qt[s], qg[s], kb);

    // O^T += V^T @ P^T — V-frags shared by both q-sets
#pragma unroll
    for (int df = 0; df < 4; ++df) {
      unsigned a = vbase + df * 2048;
      s16x4 vf0 = tr16<0>(a);
      s16x4 vf1 = tr16<512>(a);
      s16x4 vf2 = tr16<1024>(a);
      s16x4 vf3 = tr16<1536>(a);
      asm volatile("s_waitcnt lgkmcnt(0)" ::: "memory");
      __builtin_amdgcn_sched_barrier(0);
      __builtin_amdgcn_s_setprio(1);
#pragma unroll
      for (int s = 0; s < 2; ++s) {
        if (kt <= qt[s]) {
          accO[s][df] = mfma16(vf0, pb[s][0], accO[s][df]);
          accO[s][df] = mfma16(vf1, pb[s][1], accO[s][df]);
          accO[s][df] = mfma16(vf2, pb[s][2], accO[s][df]);
          accO[s][df] = mfma16(vf3, pb[s][3], accO[s][df]);
        }
      }
      __builtin_amdgcn_s_setprio(0);
    }
  }

#pragma unroll
  for (int s = 0; s < 2; ++s) {
    const float rl = 1.0f / lr[s];
    const size_t orow = (size_t)(bb * Sz + qg[s]) * Dz + hh * 64;
#pragma unroll
    for (int df = 0; df < 4; ++df) {
      s16x4 o;
#pragma unroll
      for (int j = 0; j < 4; ++j) o[j] = (short)f2bu(accO[s][df][j] * rl);
      *(s16x4*)&outA[orow + df * 16 + kgrp * 4] = o;
    }
  }
}

// ---------------- launch ----------------

extern "C" void kernel_launch(void* const* d_in, const int* in_sizes, int n_in,
                              void* d_out, int out_size, void* d_ws, size_t ws_size,
                              hipStream_t stream) {
  const float* x   = (const float*)d_in[0];
  // d_in[1] = mask (causal, known) — unused
  const float* wq  = (const float*)d_in[2];
  const float* wk  = (const float*)d_in[3];
  const float* wv  = (const float*)d_in[4];
  const float* wo  = (const float*)d_in[5];
  const float* w1  = (const float*)d_in[6];
  const float* b1  = (const float*)d_in[7];
  const float* w2  = (const float*)d_in[8];
  const float* b2  = (const float*)d_in[9];
  const float* g1  = (const float*)d_in[10];
  const float* be1 = (const float*)d_in[11];
  const float* g2  = (const float*)d_in[12];
  const float* be2 = (const float*)d_in[13];
  float* out = (float*)d_out;

  char* ws = (char*)d_ws;
  unsigned short* WqkvT = (unsigned short*)(ws);
  unsigned short* WoT   = (unsigned short*)(ws + 6291456);
  unsigned short* W1T   = (unsigned short*)(ws + 8388608);
  unsigned short* W2T   = (unsigned short*)(ws + 16777216);
  unsigned short* hbuf  = (unsigned short*)(ws + 25165824);
  unsigned short* big   = (unsigned short*)(ws + 41943040);  // QKV, later ff1

  dim3 tb(32, 8);
  pack_qkv<<<768, 256, 0, stream>>>(wq, wk, wv, WqkvT);
  transpose_f32_to_bf16<<<dim3(32, 32), tb, 0, stream>>>(wo, WoT, 1024, 1024);
  transpose_f32_to_bf16<<<dim3(128, 32), tb, 0, stream>>>(w1, W1T, 1024, 4096);
  transpose_f32_to_bf16<<<dim3(32, 128), tb, 0, stream>>>(w2, W2T, 4096, 1024);

  ln_kernel<<<Mz, 256, 0, stream>>>(x, g1, be1, hbuf);
  gemm128<EPI_BF16><<<1536, 256, 0, stream>>>(
      hbuf, WqkvT, Mz, 3072, 1024, nullptr, nullptr, big, nullptr);
  attn_kernel<<<dim3(16, 16, 4), 256, 0, stream>>>(big, hbuf);
  gemm128<EPI_RES_F32><<<512, 256, 0, stream>>>(
      hbuf, WoT, Mz, 1024, 1024, nullptr, x, nullptr, out);
  ln_kernel<<<Mz, 256, 0, stream>>>(out, g2, be2, hbuf);
  gemm128<EPI_GELU_BF16><<<2048, 256, 0, stream>>>(
      hbuf, W1T, Mz, Fz, 1024, b1, nullptr, big, nullptr);
  gemm128<EPI_BIAS_RES_F32><<<512, 256, 0, stream>>>(
      big, W2T, Mz, 1024, Fz, b2, out, nullptr, out);
}

// Round 18
// 413.205 us; speedup vs baseline: 1.0583x; 1.0051x over previous
//
#include <hip/hip_runtime.h>
#include <hip/hip_bf16.h>
#include <math.h>

// GPT decoder layer, MI355X/gfx950. bf16 MFMA GEMMs + fused flash attention.
// B=4 S=2048 D=1024 H=16 DH=64 F=4096.  Workspace layout (bytes):
//   [0,6M)      WqkvT  bf16 [3072][1024]   (pre-transposed, k-contiguous)
//   [6M,8M)     WoT    bf16 [1024][1024]
//   [8M,16M)    W1T    bf16 [4096][1024]
//   [16M,24M)   W2T    bf16 [1024][4096]
//   [24M,40M)   hbuf   bf16 [8192][1024]   (h -> attn_out -> h2, reused)
//   [40M,104M)  big    bf16                (QKV [8192][3072], later ff1 [8192][4096])

#define Bz 4
#define Sz 2048
#define Dz 1024
#define Hz 16
#define DHz 64
#define Fz 4096
#define Mz 8192

typedef float f32x4 __attribute__((ext_vector_type(4)));
typedef __bf16 bf16x8 __attribute__((ext_vector_type(8)));
typedef __bf16 bf16x4 __attribute__((ext_vector_type(4)));
typedef short s16x4 __attribute__((ext_vector_type(4)));

#define GLOAD_LDS16(g, l)                                                                   \
  __builtin_amdgcn_global_load_lds((const __attribute__((address_space(1))) unsigned int*)(g), \
                                   (__attribute__((address_space(3))) unsigned int*)(l), 16, 0, 0)

static __device__ __forceinline__ unsigned short f2bu(float f) {
  unsigned int u = __float_as_uint(f);
  u += 0x7fffu + ((u >> 16) & 1u);   // RNE to bf16
  return (unsigned short)(u >> 16);
}

static __device__ __forceinline__ f32x4 mfma32(bf16x8 a, bf16x8 b, f32x4 c) {
  return __builtin_amdgcn_mfma_f32_16x16x32_bf16(a, b, c, 0, 0, 0);
}
static __device__ __forceinline__ f32x4 mfma16(s16x4 a, s16x4 b, f32x4 c) {
#if __has_builtin(__builtin_amdgcn_mfma_f32_16x16x16bf16_1k)
  return __builtin_amdgcn_mfma_f32_16x16x16bf16_1k(a, b, c, 0, 0, 0);
#else
  asm("v_mfma_f32_16x16x16_bf16 %0, %1, %2, %0" : "+v"(c) : "v"(a), "v"(b));
  return c;
#endif
}

// hardware transpose read: lane l elem j <- lds[base + (l&15) + j*16 + (l>>4)*64] (bf16 elems)
template <int OFF>
static __device__ __forceinline__ s16x4 tr16(unsigned addr) {
  s16x4 r;
  asm volatile("ds_read_b64_tr_b16 %0, %1 offset:%2" : "=v"(r) : "v"(addr), "i"(OFF));
  return r;
}

// erf via Abramowitz-Stegun 7.1.26 (max |err| 1.5e-7 -- exact at bf16 output
// precision). ~13 VALU ops vs ~40 for the ocml erff libcall.
static __device__ __forceinline__ float erf_fast(float x) {
  float ax = fabsf(x);
  float t = __builtin_amdgcn_rcpf(fmaf(0.3275911f, ax, 1.0f));
  float poly = fmaf(fmaf(fmaf(fmaf(1.061405429f, t, -1.453152027f),
                              t, 1.421413741f),
                         t, -0.284496736f),
                    t, 0.254829592f) * t;
  float e = exp2f(ax * ax * -1.4426950408889634f);
  float er = fmaf(-poly, e, 1.0f);
  return copysignf(er, x);
}

// ---------------- weight packing ----------------

__global__ __launch_bounds__(256) void pack_qkv(
    const float* __restrict__ wq, const float* __restrict__ wk, const float* __restrict__ wv,
    unsigned short* __restrict__ outW)  // [3072][1024], row n = proj*1024 + h*64 + e, col = d
{
  __shared__ float tile[64][65];
  const int blk = blockIdx.x;       // 768 = 16 dchunk x 16 h x 3 proj
  const int dc = blk & 15;
  const int h  = (blk >> 4) & 15;
  const int p  = blk >> 8;
  const float* w = p == 0 ? wq : (p == 1 ? wk : wv);
  const int tid = threadIdx.x;
#pragma unroll
  for (int i = 0; i < 4; ++i) {
    int idx = i * 256 + tid;
    int dl = idx >> 4;
    int e0 = (idx & 15) * 4;
    const float4 v = *(const float4*)&w[(size_t)(h * 1024 + dc * 64 + dl) * 64 + e0];
    tile[dl][e0 + 0] = v.x; tile[dl][e0 + 1] = v.y;
    tile[dl][e0 + 2] = v.z; tile[dl][e0 + 3] = v.w;
  }
  __syncthreads();
#pragma unroll
  for (int i = 0; i < 4; ++i) {
    int idx = i * 256 + tid;
    int e = idx >> 4;
    int d0 = (idx & 15) * 4;
    ushort4 o;
    o.x = f2bu(tile[d0 + 0][e]); o.y = f2bu(tile[d0 + 1][e]);
    o.z = f2bu(tile[d0 + 2][e]); o.w = f2bu(tile[d0 + 3][e]);
    *(ushort4*)&outW[(size_t)(p * 1024 + h * 64 + e) * 1024 + dc * 64 + d0] = o;
  }
}

__global__ __launch_bounds__(256) void transpose_f32_to_bf16(
    const float* __restrict__ in, unsigned short* __restrict__ out, int R, int C)
{ // in [R][C] fp32 -> out [C][R] bf16
  __shared__ float tile[32][33];
  int c0 = blockIdx.x * 32, r0 = blockIdx.y * 32;
  int x = threadIdx.x, y = threadIdx.y;
#pragma unroll
  for (int i = 0; i < 32; i += 8)
    tile[y + i][x] = in[(size_t)(r0 + y + i) * C + c0 + x];
  __syncthreads();
#pragma unroll
  for (int i = 0; i < 32; i += 8)
    out[(size_t)(c0 + y + i) * R + r0 + x] = f2bu(tile[x][y + i]);
}

// ---------------- layernorm: one WAVE per row, 4 rows/block, no LDS/barriers ----------
// R17 ln used 256 threads per row with cross-wave LDS reduce + 2 barriers (~50%
// of BW floor). Now each wave owns a full row: lane holds 4 stride-64 float4s,
// wave-local shfl_xor reduce only. Grid 2048 (= 8192 rows / 4 per block).

__global__ __launch_bounds__(256) void ln_kernel(
    const float* __restrict__ x, const float* __restrict__ gamma, const float* __restrict__ beta,
    unsigned short* __restrict__ outH)
{
  const int lane = threadIdx.x & 63;
  const int wv = threadIdx.x >> 6;
  const int row = blockIdx.x * 4 + wv;
  const float4* xr = (const float4*)(x + (size_t)row * Dz);
  float4 v[4];
  float s = 0.0f, s2 = 0.0f;
#pragma unroll
  for (int i = 0; i < 4; ++i) {
    v[i] = xr[lane + i * 64];
    s += v[i].x + v[i].y + v[i].z + v[i].w;
    s2 += v[i].x * v[i].x + v[i].y * v[i].y + v[i].z * v[i].z + v[i].w * v[i].w;
  }
#pragma unroll
  for (int o = 32; o > 0; o >>= 1) {
    s += __shfl_xor(s, o);
    s2 += __shfl_xor(s2, o);
  }
  const float mean = s * (1.0f / Dz);
  const float rstd = rsqrtf(s2 * (1.0f / Dz) - mean * mean + 1e-5f);
  ushort4* orow = (ushort4*)(outH + (size_t)row * Dz);
#pragma unroll
  for (int i = 0; i < 4; ++i) {
    const float4 g4 = ((const float4*)gamma)[lane + i * 64];
    const float4 b4 = ((const float4*)beta)[lane + i * 64];
    ushort4 o;
    o.x = f2bu((v[i].x - mean) * rstd * g4.x + b4.x);
    o.y = f2bu((v[i].y - mean) * rstd * g4.y + b4.y);
    o.z = f2bu((v[i].z - mean) * rstd * g4.z + b4.z);
    o.w = f2bu((v[i].w - mean) * rstd * g4.w + b4.w);
    orow[lane + i * 64] = o;
  }
}

// ---------------- GEMM m97-structure: 128x128, BK=64, 256 thr / 4 waves, 4 blk/CU ----
// (R17-exact, best measured: total 415us.)
// Single-buffered, plain __syncthreads staging (m99/m100), unpinned compute
// (m141/R9), (row&7)/128B-span XOR swizzle (0 conflicts), bijective XCD swizzle,
// erf_fast GELU epilogue.

enum { EPI_BF16 = 0, EPI_GELU_BF16 = 1, EPI_RES_F32 = 2, EPI_BIAS_RES_F32 = 3 };

template <int EPI>
__global__ __launch_bounds__(256, 4) void gemm128(
    const unsigned short* __restrict__ A,   // [M,K] bf16
    const unsigned short* __restrict__ BT,  // [N,K] bf16
    int M, int N, int K,
    const float* bias, const float* resid,  // resid/outf may alias: no __restrict__
    unsigned short* outb, float* outf)
{
  constexpr int BK = 64;
  __shared__ unsigned short As[128 * BK];  // [row][64k], 16B chunks, (row&7) XOR
  __shared__ unsigned short Bs[128 * BK];
  const int tid = threadIdx.x;
  const int lane = tid & 63;
  const int wid = tid >> 6;
  const int wm = (wid >> 1) * 64;
  const int wn = (wid & 1) * 64;
  const int rsel = lane & 15;
  const int kgrp = lane >> 4;

  // XCD-chunked bijective swizzle (nwg % 8 == 0 for all our grids)
  const int nwg = gridDim.x;
  const int bid = blockIdx.x;
  const int id2 = (bid & 7) * (nwg >> 3) + (bid >> 3);
  const int nbx = N / 128;
  const int n0 = (id2 % nbx) * 128;
  const int m0 = (id2 / nbx) * 128;

  f32x4 acc[4][4] = {};

  const int T = K >> 6;
  for (int t = 0; t < T; ++t) {
    if (t) __syncthreads();
    const int kOff = t * BK;
#pragma unroll
    for (int r = 0; r < 4; ++r) {          // 1024 chunks of 16B per matrix tile
      int gc = r * 256 + tid;
      int row = gc >> 3;
      int kcs = (gc & 7) ^ (row & 7);      // proven 128B-span swizzle (0 conflicts)
      GLOAD_LDS16(A + (size_t)(m0 + row) * K + kOff + kcs * 8, &As[gc * 8]);
      GLOAD_LDS16(BT + (size_t)(n0 + row) * K + kOff + kcs * 8, &Bs[gc * 8]);
    }
    __syncthreads();
#pragma unroll
    for (int kk = 0; kk < 2; ++kk) {
      bf16x8 af[4], bfr[4];
#pragma unroll
      for (int mf = 0; mf < 4; ++mf) {
        int ar = wm + mf * 16 + rsel;
        af[mf] = *(const bf16x8*)&As[ar * BK + (((kk * 4 + kgrp) ^ (ar & 7)) * 8)];
      }
#pragma unroll
      for (int nf = 0; nf < 4; ++nf) {
        int br = wn + nf * 16 + rsel;
        bfr[nf] = *(const bf16x8*)&Bs[br * BK + (((kk * 4 + kgrp) ^ (br & 7)) * 8)];
      }
      // unpinned: compiler emits fine-grained lgkmcnt and co-schedules with MFMA
#pragma unroll
      for (int mf = 0; mf < 4; ++mf)
#pragma unroll
        for (int nf = 0; nf < 4; ++nf)
          acc[mf][nf] = mfma32(af[mf], bfr[nf], acc[mf][nf]);
    }
  }

#pragma unroll
  for (int mf = 0; mf < 4; ++mf) {
#pragma unroll
    for (int nf = 0; nf < 4; ++nf) {
      const int n = n0 + wn + nf * 16 + rsel;
#pragma unroll
      for (int j = 0; j < 4; ++j) {
        const int m = m0 + wm + mf * 16 + kgrp * 4 + j;
        const size_t idx = (size_t)m * N + n;
        float v = acc[mf][nf][j];
        if constexpr (EPI == EPI_BF16) {
          outb[idx] = f2bu(v);
        } else if constexpr (EPI == EPI_GELU_BF16) {
          v += bias[n];
          v = 0.5f * v * (1.0f + erf_fast(v * 0.70710678118654752f));
          outb[idx] = f2bu(v);
        } else if constexpr (EPI == EPI_RES_F32) {
          outf[idx] = v + resid[idx];
        } else {
          outf[idx] = v + bias[n] + resid[idx];
        }
      }
    }
  }
}

// ---------------- fused causal flash attention (R17-exact) ----------
// Block = PAIR of q-tiles {i, 31-i} x head x batch, grid 1024 = 4 blocks/CU.
// S^T = K @ Q^T via mfma 16x16x32; P^T stays in registers as the B-frag of
// mfma 16x16x16 for O^T = V^T @ P^T; V read with ds_read_b64_tr_b16, V-frags
// shared by both q-sets. Softmax in log2 domain with defer-rescale (THR=8);
// mask/max in raw-score domain, p = exp2(fma(sc, SCL, -m)).
// NOTE: loop-body perturbations (R12 dbuf, R15 ones-MFMA) both regressed via
// broken K/V L2 co-timing of paired blocks (+25-30MB FETCH) -- do not perturb.

__global__ __launch_bounds__(256, 4) void attn_kernel(
    const unsigned short* __restrict__ QKV,  // [Mz][3072] bf16 (q|k|v, feature h*64+e)
    unsigned short* __restrict__ outA)       // [Mz][Dz]  bf16
{
  __shared__ unsigned short Kt[64 * 64];  // [key][d], 16B d-chunk XOR-swizzled by key&7
  __shared__ unsigned short Vs[64 * 64];  // subtiled for tr16 reads
  const int pi = blockIdx.x;  // 0..15
  const int hh = blockIdx.y;
  const int bb = blockIdx.z;
  const int tid = threadIdx.x;
  const int lane = tid & 63;
  const int w = tid >> 6;
  const int rsel = lane & 15;
  const int kgrp = lane >> 4;
  const int qt[2] = {pi, 31 - pi};

  bf16x8 qf0[2], qf1[2];
  int qg[2];
#pragma unroll
  for (int s = 0; s < 2; ++s) {
    qg[s] = qt[s] * 64 + w * 16 + rsel;
    const size_t rowQ = (size_t)(bb * Sz + qg[s]) * 3072 + hh * 64;
    qf0[s] = *(const bf16x8*)&QKV[rowQ + kgrp * 8];
    qf1[s] = *(const bf16x8*)&QKV[rowQ + 32 + kgrp * 8];
  }

  f32x4 accO[2][4] = {};  // [set][df]; O^T row=d=(df*16+kgrp*4+j), col=q=rsel
  float mr[2] = {-INFINITY, -INFINITY};
  float lr[2] = {0.0f, 0.0f};

  auto vs3 = (__attribute__((address_space(3))) unsigned short*)Vs;
  const unsigned vbase = (unsigned)(uintptr_t)vs3 + (unsigned)lane * 8u;
  constexpr float SCL = 0.18033688011112042f;  // log2(e)/sqrt(64)

  // S^T + online softmax -> P^T bf16 B-frags. Raw-domain max; FMA-folded exp arg.
  auto proc = [&](const bf16x8& q0, const bf16x8& q1, float& mrun, float& lrun,
                  f32x4* accS, s16x4* pb, bool edge, int qgs, int kb) {
    f32x4 sc[4];
    __builtin_amdgcn_s_setprio(1);
#pragma unroll
    for (int kf = 0; kf < 4; ++kf) {
      int key = kf * 16 + rsel;
      bf16x8 k0 = *(const bf16x8*)&Kt[key * 64 + ((kgrp ^ (key & 7)) * 8)];
      bf16x8 k1 = *(const bf16x8*)&Kt[key * 64 + (((4 + kgrp) ^ (key & 7)) * 8)];
      f32x4 s = {};
      s = mfma32(k0, q0, s);
      s = mfma32(k1, q1, s);
      sc[kf] = s;
    }
    __builtin_amdgcn_s_setprio(0);
    float tmax = -INFINITY;
#pragma unroll
    for (int kf = 0; kf < 4; ++kf)
#pragma unroll
      for (int j = 0; j < 4; ++j) {
        if (edge) {
          int keyg = kb + kf * 16 + kgrp * 4 + j;
          if (keyg > qgs) sc[kf][j] = -INFINITY;
        }
        tmax = fmaxf(tmax, sc[kf][j]);
      }
    tmax = fmaxf(tmax, __shfl_xor(tmax, 16));
    tmax = fmaxf(tmax, __shfl_xor(tmax, 32));
    const float tmaxs = tmax * SCL;   // scale once, after the reduce
    // defer-rescale (T13): skip O/l rescale while max growth stays under 8 (log2 units)
    if (!__all(tmaxs <= mrun + 8.0f)) {
      const float mnew = fmaxf(mrun, tmaxs);
      const float corr = exp2f(mrun - mnew);
      lrun *= corr;
#pragma unroll
      for (int df = 0; df < 4; ++df) accS[df] *= corr;
      mrun = mnew;
    }
    float psum = 0.0f;
#pragma unroll
    for (int kf = 0; kf < 4; ++kf) {
      bf16x4 pv;
#pragma unroll
      for (int j = 0; j < 4; ++j) {
        float e = exp2f(fmaf(sc[kf][j], SCL, -mrun));  // one v_fma + v_exp
        psum += e;
        pv[j] = (__bf16)e;  // v_cvt_pk_bf16_f32 pairs
      }
      pb[kf] = __builtin_bit_cast(s16x4, pv);
    }
    psum += __shfl_xor(psum, 16);
    psum += __shfl_xor(psum, 32);
    lrun += psum;
  };

  for (int kt = 0; kt <= qt[1]; ++kt) {
    const int kb = kt * 64;
    if (kt) __syncthreads();  // prev tile's LDS reads done before overwrite
    // stage K: LDS linear, global d-chunk XOR-swizzled by key&7
#pragma unroll
    for (int r = 0; r < 2; ++r) {
      int c = r * 256 + tid;
      int key = c >> 3;
      int dcs = (c & 7) ^ (key & 7);
      GLOAD_LDS16(QKV + (size_t)(bb * Sz + kb + key) * 3072 + 1024 + hh * 64 + dcs * 8,
                  &Kt[c * 8]);
    }
    // stage V: LDS linear; source permuted so LDS holds subtiled layout
#pragma unroll
    for (int r = 0; r < 2; ++r) {
      int c = r * 256 + tid;
      int key = ((c >> 3) & 15) * 4 + ((c >> 1) & 3);
      int d = (c >> 7) * 16 + (c & 1) * 8;
      GLOAD_LDS16(QKV + (size_t)(bb * Sz + kb + key) * 3072 + 2048 + hh * 64 + d,
                  &Vs[c * 8]);
    }
    __syncthreads();

    s16x4 pb[2][4];
#pragma unroll
    for (int s = 0; s < 2; ++s)
      if (kt <= qt[s])
        proc(qf0[s], qf1[s], mr[s], lr[s], accO[s], pb[s], kt == qt[s], qg[s], kb);

    // O^T += V^T @ P^T — V-frags shared by both q-sets
#pragma unroll
    for (int df = 0; df < 4; ++df) {
      unsigned a = vbase + df * 2048;
      s16x4 vf0 = tr16<0>(a);
      s16x4 vf1 = tr16<512>(a);
      s16x4 vf2 = tr16<1024>(a);
      s16x4 vf3 = tr16<1536>(a);
      asm volatile("s_waitcnt lgkmcnt(0)" ::: "memory");
      __builtin_amdgcn_sched_barrier(0);
      __builtin_amdgcn_s_setprio(1);
#pragma unroll
      for (int s = 0; s < 2; ++s) {
        if (kt <= qt[s]) {
          accO[s][df] = mfma16(vf0, pb[s][0], accO[s][df]);
          accO[s][df] = mfma16(vf1, pb[s][1], accO[s][df]);
          accO[s][df] = mfma16(vf2, pb[s][2], accO[s][df]);
          accO[s][df] = mfma16(vf3, pb[s][3], accO[s][df]);
        }
      }
      __builtin_amdgcn_s_setprio(0);
    }
  }

#pragma unroll
  for (int s = 0; s < 2; ++s) {
    const float rl = 1.0f / lr[s];
    const size_t orow = (size_t)(bb * Sz + qg[s]) * Dz + hh * 64;
#pragma unroll
    for (int df = 0; df < 4; ++df) {
      s16x4 o;
#pragma unroll
      for (int j = 0; j < 4; ++j) o[j] = (short)f2bu(accO[s][df][j] * rl);
      *(s16x4*)&outA[orow + df * 16 + kgrp * 4] = o;
    }
  }
}

// ---------------- launch ----------------

extern "C" void kernel_launch(void* const* d_in, const int* in_sizes, int n_in,
                              void* d_out, int out_size, void* d_ws, size_t ws_size,
                              hipStream_t stream) {
  const float* x   = (const float*)d_in[0];
  // d_in[1] = mask (causal, known) — unused
  const float* wq  = (const float*)d_in[2];
  const float* wk  = (const float*)d_in[3];
  const float* wv  = (const float*)d_in[4];
  const float* wo  = (const float*)d_in[5];
  const float* w1  = (const float*)d_in[6];
  const float* b1  = (const float*)d_in[7];
  const float* w2  = (const float*)d_in[8];
  const float* b2  = (const float*)d_in[9];
  const float* g1  = (const float*)d_in[10];
  const float* be1 = (const float*)d_in[11];
  const float* g2  = (const float*)d_in[12];
  const float* be2 = (const float*)d_in[13];
  float* out = (float*)d_out;

  char* ws = (char*)d_ws;
  unsigned short* WqkvT = (unsigned short*)(ws);
  unsigned short* WoT   = (unsigned short*)(ws + 6291456);
  unsigned short* W1T   = (unsigned short*)(ws + 8388608);
  unsigned short* W2T   = (unsigned short*)(ws + 16777216);
  unsigned short* hbuf  = (unsigned short*)(ws + 25165824);
  unsigned short* big   = (unsigned short*)(ws + 41943040);  // QKV, later ff1

  dim3 tb(32, 8);
  pack_qkv<<<768, 256, 0, stream>>>(wq, wk, wv, WqkvT);
  transpose_f32_to_bf16<<<dim3(32, 32), tb, 0, stream>>>(wo, WoT, 1024, 1024);
  transpose_f32_to_bf16<<<dim3(128, 32), tb, 0, stream>>>(w1, W1T, 1024, 4096);
  transpose_f32_to_bf16<<<dim3(32, 128), tb, 0, stream>>>(w2, W2T, 4096, 1024);

  ln_kernel<<<2048, 256, 0, stream>>>(x, g1, be1, hbuf);
  gemm128<EPI_BF16><<<1536, 256, 0, stream>>>(
      hbuf, WqkvT, Mz, 3072, 1024, nullptr, nullptr, big, nullptr);
  attn_kernel<<<dim3(16, 16, 4), 256, 0, stream>>>(big, hbuf);
  gemm128<EPI_RES_F32><<<512, 256, 0, stream>>>(
      hbuf, WoT, Mz, 1024, 1024, nullptr, x, nullptr, out);
  ln_kernel<<<2048, 256, 0, stream>>>(out, g2, be2, hbuf);
  gemm128<EPI_GELU_BF16><<<2048, 256, 0, stream>>>(
      hbuf, W1T, Mz, Fz, 1024, b1, nullptr, big, nullptr);
  gemm128<EPI_BIAS_RES_F32><<<512, 256, 0, stream>>>(
      big, W2T, Mz, 1024, Fz, b2, out, nullptr, out);
}